// Round 18
// baseline (213.568 us; speedup 1.0000x reference)
//
#include <hip/hip_runtime.h>
#include <hip/hip_bf16.h>

typedef unsigned short u16;
typedef unsigned int   u32;
typedef __attribute__((ext_vector_type(8)))  short v8s;
typedef __attribute__((ext_vector_type(4)))  float v4f;
typedef __attribute__((ext_vector_type(16))) float v16f;
typedef __attribute__((ext_vector_type(4)))  u32   v4u;
typedef __attribute__((ext_vector_type(2)))  u32   v2u;

#define B_      2
#define N_      1024
#define C_      1024
#define H_      16
#define BH_     32
#define PAST_   8192
#define BUDGET  4000
#define ANCHOR_ 512
#define NCAND   8704
#define NOLD    7680
#define KEEPN   3488
#define NSPLIT  8
#define KSLICE  2097152
#define QSCALE  0.18033688011112042f   /* 0.125 * log2(e) : softmax in log2 domain */

__device__ __forceinline__ u16 f2bf(float f) {
    u32 u = __float_as_uint(f);
    u32 r = u + 0x7fffu + ((u >> 16) & 1u);
    return (u16)(r >> 16);
}
__device__ __forceinline__ float bf2f(u16 h) {
    return __uint_as_float(((u32)h) << 16);
}
__device__ __forceinline__ u32 pk2(float a, float b) {
    __hip_bfloat162 t = __float22bfloat162_rn(float2{a, b});
    u32 r; __builtin_memcpy(&r, &t, 4); return r;
}
__device__ __forceinline__ v8s mk8(u32 a, u32 b, u32 c, u32 d) {
    v4u t; t[0] = a; t[1] = b; t[2] = c; t[3] = d;
    return __builtin_bit_cast(v8s, t);
}
__device__ __forceinline__ void glds16(const u16* g, u16* l) {
    __builtin_amdgcn_global_load_lds((const __attribute__((address_space(1))) u32*)g,
                                     (__attribute__((address_space(3))) u32*)l, 16, 0, 0);
}

// ---------------- K0: prep (hi/lo split, DEDUP'd concat operands), 4 elems/thread ----------------
// xcat (2048 x 2048) = [x_hi | x_lo]; wcat (3072 x 2048) = [w_hi | w_lo]
__global__ void prep(const float* __restrict__ x, const float* __restrict__ qw,
                     const float* __restrict__ pw, u16* __restrict__ xcat,
                     u16* __restrict__ wcat, u16* __restrict__ wpbf) {
    const int i = (blockIdx.x * 256 + threadIdx.x) << 2;
    const int NX = 2048 * 1024, NW = 3072 * 1024;
    if (i < NX) {
        const v4f v = *(const v4f*)(x + i);
        union { u16 h[4]; v2u u; } hi, lo;
        #pragma unroll
        for (int e = 0; e < 4; ++e) {
            hi.h[e] = f2bf(v[e]);
            lo.h[e] = f2bf(v[e] - bf2f(hi.h[e]));
        }
        const int m = i >> 10, k = i & 1023;
        u16* p = xcat + (size_t)m * 2048 + k;
        *(v2u*)p = hi.u; *(v2u*)(p + 1024) = lo.u;
    } else if (i < NX + NW) {
        const int j = i - NX;
        const v4f v = *(const v4f*)(qw + j);
        union { u16 h[4]; v2u u; } hi, lo;
        #pragma unroll
        for (int e = 0; e < 4; ++e) {
            hi.h[e] = f2bf(v[e]);
            lo.h[e] = f2bf(v[e] - bf2f(hi.h[e]));
        }
        const int n = j >> 10, k = j & 1023;
        u16* p = wcat + (size_t)n * 2048 + k;
        *(v2u*)p = hi.u; *(v2u*)(p + 1024) = lo.u;
    } else {
        const int j = i - NX - NW;
        const v4f v = *(const v4f*)(pw + j);
        union { u16 h[4]; v2u u; } hv;
        #pragma unroll
        for (int e = 0; e < 4; ++e) hv.h[e] = f2bf(v[e]);
        *(v2u*)(wpbf + j) = hv.u;
    }
}

// ---------------- K1: QKV GEMM, uniform split-K, 64x128 tile, BK=64 ----------------
// grid 1280: Q(256), V(256), K(3x256 slices). Per-operand column base selects
// the hi/lo slice: s0 = x_hi*w_hi, s1 = x_hi*w_lo, s2 = x_lo*w_hi.
// global_load_lds staging, XOR-swizzled SOURCE granule, XOR'd reads -> conflict-free.
__global__ __launch_bounds__(256) void gemm_qkv(
    const u16* __restrict__ A, const u16* __restrict__ Bm,
    const float* __restrict__ bias,
    u16* __restrict__ Qbf, float* __restrict__ Vnew, float* __restrict__ Kpart) {
    __shared__ u16 As[64 * 64];
    __shared__ u16 Bs[128 * 64];
    const int tid = threadIdx.x;
    const int l = tid & 63, w = tid >> 6;
    const int wm = w >> 1, wn = w & 1;
    const int bid = blockIdx.x;
    int tsel, by, bx, s;
    if (bid < 256)      { tsel = 0; s = 0; const int r = bid;       by = r >> 3; bx = r & 7; }
    else if (bid < 512) { tsel = 2; s = 0; const int r = bid - 256; by = r >> 3; bx = r & 7; }
    else                { const int rr = bid - 512; s = rr >> 8; const int r = rr & 255;
                          tsel = 1; by = r >> 3; bx = r & 7; }
    const int ksA = (s == 2) ? 1024 : 0;   // x_lo only for slice 2
    const int ksB = (s == 1) ? 1024 : 0;   // w_lo only for slice 1
    const int nbase = tsel * 1024 + bx * 128;

    v4f acc[2][4];
    #pragma unroll
    for (int a = 0; a < 2; ++a)
        #pragma unroll
        for (int b = 0; b < 4; ++b) { acc[a][b][0]=0.f; acc[a][b][1]=0.f; acc[a][b][2]=0.f; acc[a][b][3]=0.f; }

    const int lrow = l >> 3;                 // 0..7 within 8-row stripe
    const int lgr  = (l & 7) ^ lrow;         // pre-swizzled source granule
    const u16* pa = A  + ((size_t)(by * 64 + w * 16 + lrow)) * 2048 + ksA + lgr * 8;
    const u16* pb = Bm + ((size_t)(nbase + w * 32 + lrow))   * 2048 + ksB + lgr * 8;

    for (int k0 = 0; k0 < 1024; k0 += 64) {
        if (k0) __syncthreads();
        #pragma unroll
        for (int j = 0; j < 2; ++j)
            glds16(pa + j * 16384 + k0, &As[w * 1024 + j * 512]);
        #pragma unroll
        for (int j = 0; j < 4; ++j)
            glds16(pb + j * 16384 + k0, &Bs[w * 2048 + j * 512]);
        __syncthreads();
        #pragma unroll
        for (int kc = 0; kc < 2; ++kc) {
            v8s af[2], bfr[4];
            #pragma unroll
            for (int mt = 0; mt < 2; ++mt) {
                const int R = wm * 32 + mt * 16 + (l & 15);
                const int g = (kc * 4 + (l >> 4)) ^ (R & 7);
                af[mt] = *(const v8s*)(&As[R * 64 + g * 8]);
            }
            #pragma unroll
            for (int nt = 0; nt < 4; ++nt) {
                const int R = wn * 64 + nt * 16 + (l & 15);
                const int g = (kc * 4 + (l >> 4)) ^ (R & 7);
                bfr[nt] = *(const v8s*)(&Bs[R * 64 + g * 8]);
            }
            #pragma unroll
            for (int mt = 0; mt < 2; ++mt)
                #pragma unroll
                for (int nt = 0; nt < 4; ++nt)
                    acc[mt][nt] = __builtin_amdgcn_mfma_f32_16x16x32_bf16(af[mt], bfr[nt], acc[mt][nt], 0, 0, 0);
        }
    }
    // epilogue: head-layout (bb*16+hh, nn, dd)
    #pragma unroll
    for (int nt = 0; nt < 4; ++nt) {
        const int nl = bx * 128 + wn * 64 + nt * 16 + (l & 15);   // [0,1024)
        const int hh = nl >> 6, dd = nl & 63;
        const float bv = bias[tsel * 1024 + nl];
        #pragma unroll
        for (int mt = 0; mt < 2; ++mt)
            #pragma unroll
            for (int r = 0; r < 4; ++r) {
                const int m = by * 64 + wm * 32 + mt * 16 + (l >> 4) * 4 + r;
                const int bb = m >> 10, nn = m & 1023;
                const size_t o = (((size_t)(bb * 16 + hh)) * 1024 + nn) * 64 + dd;
                if (tsel == 0)      Qbf[o] = f2bf((acc[mt][nt][r] + bv) * QSCALE);
                else if (tsel == 2) Vnew[o] = acc[mt][nt][r] + bv;
                else                Kpart[(size_t)s * KSLICE + o] = acc[mt][nt][r] + (s == 0 ? bv : 0.f);
            }
    }
}

// ---------------- K2: normalized-row sums; K-new rows summed from 3 slices inline ----------------
__global__ __launch_bounds__(256) void kmean(const float* __restrict__ past_k,
                                             const float* __restrict__ Kp,
                                             float* __restrict__ part) {
    __shared__ float Asum[4][64];
    const int blk = blockIdx.x, tid = threadIdx.x;
    const int bh = blk / 34, seg = blk % 34;
    const int l = tid & 63, w = tid >> 6;
    const int rr = l >> 4, dd = l & 15;
    v4f acc; acc[0]=0.f; acc[1]=0.f; acc[2]=0.f; acc[3]=0.f;
    const int base = seg * 256 + w * 64;
    for (int q4 = 0; q4 < 64; q4 += 4) {
        const int i = base + q4 + rr;
        v4f v;
        if (i < NOLD) {
            v = *(const v4f*)(past_k + (((size_t)bh * PAST_) + ANCHOR_ + i) * 64 + dd * 4);
        } else {
            const float* r0 = Kp + (((size_t)bh * N_) + (i - NOLD)) * 64 + dd * 4;
            v4f a = *(const v4f*)r0;
            v4f b = *(const v4f*)(r0 + KSLICE);
            v4f c = *(const v4f*)(r0 + 2 * KSLICE);
            #pragma unroll
            for (int e = 0; e < 4; ++e) v[e] = (a[e] + b[e]) + c[e];
        }
        float ss = v[0]*v[0] + v[1]*v[1] + v[2]*v[2] + v[3]*v[3];
        ss += __shfl_xor(ss, 1); ss += __shfl_xor(ss, 2);
        ss += __shfl_xor(ss, 4); ss += __shfl_xor(ss, 8);
        const float rn = 1.0f / fmaxf(sqrtf(ss), 1e-12f);
        acc[0] += v[0]*rn; acc[1] += v[1]*rn; acc[2] += v[2]*rn; acc[3] += v[3]*rn;
    }
    #pragma unroll
    for (int e = 0; e < 4; ++e) { acc[e] += __shfl_xor(acc[e], 16); acc[e] += __shfl_xor(acc[e], 32); }
    if (l < 16) *(v4f*)(&Asum[w][dd * 4]) = acc;
    __syncthreads();
    if (tid < 64) {
        float s = Asum[0][tid] + Asum[1][tid] + Asum[2][tid] + Asum[3][tid];
        part[((size_t)seg * BH_ + bh) * 64 + tid] = s;
    }
}

// ---------------- K3: baseline / div_avg (part-reduce fused in) ----------------
__global__ __launch_bounds__(256) void kdiv(const float* __restrict__ past_k,
                                            const float* __restrict__ part,
                                            float* __restrict__ divavg) {
    __shared__ float MV[1024];
    const int blk = blockIdx.x, tid = threadIdx.x;
    const int b = blk / 240, ib = blk % 240;
    for (int j = tid; j < 1024; j += 256) {
        const float* pp = part + b * 1024 + j;
        float s = 0.f;
        #pragma unroll
        for (int g = 0; g < 34; ++g) s += pp[(size_t)g * 2048];
        MV[j] = s / 8704.0f;
    }
    __syncthreads();
    const int l = tid & 63, w = tid >> 6;
    const int rr = l >> 4, dd = l & 15;
    for (int ii = 0; ii < 8; ++ii) {
        const int i = ib * 32 + w * 8 + ii;
        float accv = 0.f;
        #pragma unroll
        for (int hq = 0; hq < 4; ++hq) {
            const int h = hq * 4 + rr;
            const v4f v  = *(const v4f*)(past_k + (((size_t)(b * 16 + h)) * PAST_ + ANCHOR_ + i) * 64 + dd * 4);
            const v4f mv = *(const v4f*)(&MV[h * 64 + dd * 4]);
            float ss = v[0]*v[0] + v[1]*v[1] + v[2]*v[2] + v[3]*v[3];
            float dp = v[0]*mv[0] + v[1]*mv[1] + v[2]*mv[2] + v[3]*mv[3];
            ss += __shfl_xor(ss, 1); dp += __shfl_xor(dp, 1);
            ss += __shfl_xor(ss, 2); dp += __shfl_xor(dp, 2);
            ss += __shfl_xor(ss, 4); dp += __shfl_xor(dp, 4);
            ss += __shfl_xor(ss, 8); dp += __shfl_xor(dp, 8);
            accv += 1.0f - dp / fmaxf(sqrtf(ss), 1e-12f);
        }
        accv += __shfl_xor(accv, 16); accv += __shfl_xor(accv, 32);
        if (l == 0) divavg[(size_t)b * NOLD + i] = accv / 16.0f;
    }
}

// ---------------- K4: per-batch top-k (register-resident; shfl-scan compaction) ----------------
__global__ __launch_bounds__(256) void kselect(const float* __restrict__ divavg,
                                               const float* __restrict__ imp,
                                               int* __restrict__ keep) {
    __shared__ float comb[NCAND];
    __shared__ float red[16];
    __shared__ u32 scnt[2][4];
    __shared__ u32 wg_[4], we_[4];
    const int b = blockIdx.x, tid = threadIdx.x;
    const int l = tid & 63, w = tid >> 6;

    float mn = 1e30f, mx = -1e30f;
    for (int i = tid; i < NOLD; i += 256) { float v = divavg[b * NOLD + i]; mn = fminf(mn, v); mx = fmaxf(mx, v); }
    #pragma unroll
    for (int d = 1; d < 64; d <<= 1) { mn = fminf(mn, __shfl_xor(mn, d)); mx = fmaxf(mx, __shfl_xor(mx, d)); }
    if (l == 0) { red[w] = mn; red[4 + w] = mx; }
    float mn2 = 1e30f, mx2 = -1e30f;
    for (int i = tid; i < N_; i += 256) { float v = imp[b * N_ + i]; mn2 = fminf(mn2, v); mx2 = fmaxf(mx2, v); }
    #pragma unroll
    for (int d = 1; d < 64; d <<= 1) { mn2 = fminf(mn2, __shfl_xor(mn2, d)); mx2 = fmaxf(mx2, __shfl_xor(mx2, d)); }
    if (l == 0) { red[8 + w] = mn2; red[12 + w] = mx2; }
    __syncthreads();
    const float omin = fminf(fminf(red[0], red[1]), fminf(red[2], red[3]));
    const float omax = fmaxf(fmaxf(red[4], red[5]), fmaxf(red[6], red[7]));
    const float imin = fminf(fminf(red[8], red[9]), fminf(red[10], red[11]));
    const float imax = fmaxf(fmaxf(red[12], red[13]), fmaxf(red[14], red[15]));
    const float oden = omax - omin + 1e-8f, iden = imax - imin + 1e-8f;
    for (int i = tid; i < NCAND; i += 256)
        comb[i] = (i < NOLD) ? 0.5f * ((divavg[b * NOLD + i] - omin) / oden)
                             : 0.5f * ((imp[b * N_ + i - NOLD] - imin) / iden);
    __syncthreads();
    u32 fu[34];
    const int i0 = tid * 34;
    #pragma unroll
    for (int j = 0; j < 34; ++j) fu[j] = __float_as_uint(comb[i0 + j]);
    // bisection for tau = KEEPN-th largest (uint order; comb in [0, 0.5) so hi=0x3F000000 safe)
    u32 lo = 0, hi = 0x3F000000u;
    int it = 0;
    while (lo < hi) {
        const u32 mid = lo + ((hi - lo) >> 1);
        u32 c = 0;
        #pragma unroll
        for (int j = 0; j < 34; ++j) c += (fu[j] > mid) ? 1u : 0u;
        c += __shfl_xor(c, 1); c += __shfl_xor(c, 2); c += __shfl_xor(c, 4);
        c += __shfl_xor(c, 8); c += __shfl_xor(c, 16); c += __shfl_xor(c, 32);
        if (l == 0) scnt[it & 1][w] = c;
        __syncthreads();
        const u32 total = scnt[it & 1][0] + scnt[it & 1][1] + scnt[it & 1][2] + scnt[it & 1][3];
        if (total < KEEPN) hi = mid; else lo = mid + 1;
        ++it;
    }
    const u32 tau = lo;
    u32 ng = 0, ne = 0;
    #pragma unroll
    for (int j = 0; j < 34; ++j) { ng += (fu[j] > tau); ne += (fu[j] == tau); }
    // exact exclusive prefix via wave shfl-scan + per-wave offsets
    u32 gi = ng, ei = ne;
    #pragma unroll
    for (int d = 1; d < 64; d <<= 1) {
        u32 tg = __shfl_up(gi, d), te = __shfl_up(ei, d);
        if (l >= d) { gi += tg; ei += te; }
    }
    if (l == 63) { wg_[w] = gi; we_[w] = ei; }
    __syncthreads();
    u32 offg = 0, offe = 0, totg = 0;
    #pragma unroll
    for (int ww = 0; ww < 4; ++ww) {
        if (ww < w) { offg += wg_[ww]; offe += we_[ww]; }
        totg += wg_[ww];
    }
    const u32 need = KEEPN - totg;
    u32 g = offg + gi - ng;
    u32 e = offe + ei - ne;
    #pragma unroll
    for (int j = 0; j < 34; ++j) {
        const u32 u = fu[j];
        const bool kg = u > tau;
        const bool ke = (u == tau) && (e < need);
        if (kg || ke) keep[b * KEEPN + (g + (e < need ? e : need))] = 512 + i0 + j;
        g += kg ? 1u : 0u; e += (u == tau) ? 1u : 0u;
    }
}

// ---------------- K5: gather kept K/V -> bf16 Kg (row-major), VTg (transposed) ----------------
__global__ __launch_bounds__(256) void kgather(const float* __restrict__ past_k,
    const float* __restrict__ past_v, const float* __restrict__ Kp,
    const float* __restrict__ Vnew, const int* __restrict__ keep,
    u16* __restrict__ Kg, u16* __restrict__ VTg) {
    __shared__ float VL[64][65];
    const int blk = blockIdx.x, tid = threadIdx.x;
    const int bh = blk / 63, jb = blk % 63;
    const int b = bh >> 4;
    const int jj = tid >> 2, cc = tid & 3;
    const int j = jb * 64 + jj;
    if (j < BUDGET) {
        const int row = (j < ANCHOR_) ? j : keep[b * KEEPN + (j - ANCHOR_)];
        union { u16 h[16]; v4u v[2]; } pk_;
        if (row < PAST_) {
            const size_t o = ((size_t)bh * PAST_ + row) * 64;
            const float* ks = past_k + o;
            const float* vs = past_v + o;
            #pragma unroll
            for (int q4 = 0; q4 < 4; ++q4) {
                v4f kv = *(const v4f*)(ks + cc * 16 + q4 * 4);
                v4f vv = *(const v4f*)(vs + cc * 16 + q4 * 4);
                #pragma unroll
                for (int e = 0; e < 4; ++e) {
                    pk_.h[q4 * 4 + e] = f2bf(kv[e]);
                    VL[jj][cc * 16 + q4 * 4 + e] = vv[e];
                }
            }
        } else {
            const size_t o = ((size_t)bh * N_ + (row - PAST_)) * 64;
            const float* k0 = Kp + o;
            const float* vs = Vnew + o;
            #pragma unroll
            for (int q4 = 0; q4 < 4; ++q4) {
                v4f a = *(const v4f*)(k0 + cc * 16 + q4 * 4);
                v4f bb2 = *(const v4f*)(k0 + KSLICE + cc * 16 + q4 * 4);
                v4f c = *(const v4f*)(k0 + 2 * KSLICE + cc * 16 + q4 * 4);
                v4f vv = *(const v4f*)(vs + cc * 16 + q4 * 4);
                #pragma unroll
                for (int e = 0; e < 4; ++e) {
                    pk_.h[q4 * 4 + e] = f2bf((a[e] + bb2[e]) + c[e]);
                    VL[jj][cc * 16 + q4 * 4 + e] = vv[e];
                }
            }
        }
        v4u* kout = (v4u*)(Kg + ((size_t)bh * BUDGET + j) * 64 + cc * 16);
        kout[0] = pk_.v[0]; kout[1] = pk_.v[1];
    }
    __syncthreads();
    const int d = tid >> 2, c4 = tid & 3;
    const int jc = c4 * 16;
    if (jb * 64 + jc < BUDGET) {
        union { u16 h[16]; v4u v[2]; } pv_;
        #pragma unroll
        for (int t2 = 0; t2 < 16; ++t2) pv_.h[t2] = f2bf(VL[jc + t2][d]);
        v4u* vout = (v4u*)(VTg + ((size_t)bh * 64 + d) * BUDGET + jb * 64 + jc);
        vout[0] = pv_.v[0]; vout[1] = pv_.v[1];
    }
}

// ---------------- K6: flash attention, swapped QK^T, 32x32x16 MFMA (r12-proven core) ----------------
// grid 4096 x 128thr: bh(32) x qblk(16) x split(8), 2 waves/wg, each wave owns 32 q.
// 16 WG/CU queued vs 8 resident -> backfill hides drain. NO-MAX softmax, reg-staged
// dbuf LDS, prefetch AFTER barrier, raw v_exp_f32, permlane32 P-frags, XCD swizzle.
__global__ __launch_bounds__(128, 4) void attn(const u16* __restrict__ Qbf,
    const u16* __restrict__ Kg, const u16* __restrict__ VTg,
    u16* __restrict__ Opart, float* __restrict__ Lpart) {
    __shared__ u16 Ks[2][32 * 72];
    __shared__ u16 Vs[2][64 * 40];
    const int tid = threadIdx.x;
    const int l = tid & 63, w = tid >> 6;
    const int G = l >> 5, lq = l & 31;
    const int bid = ((blockIdx.x & 7) << 9) | (blockIdx.x >> 3);
    const int bh = bid >> 7, rem = bid & 127;
    const int split = rem & 7, qblk = rem >> 3;
    const int q = qblk * 64 + w * 32 + lq;
    const int t0 = split * 16;
    const int t1 = (split == 7) ? 125 : (t0 + 16);

    v8s Qf[4];
    const v8s* qp = (const v8s*)(Qbf + ((size_t)(bh * 1024 + q)) * 64);
    #pragma unroll
    for (int c = 0; c < 4; ++c) Qf[c] = qp[c * 2 + G];

    v16f o0, o1;
    #pragma unroll
    for (int e = 0; e < 16; ++e) { o0[e] = 0.f; o1[e] = 0.f; }
    float lrun = 0.f;

    const int krow = tid >> 2, kc = tid & 3;
    const int vrow = tid >> 1, vc = tid & 1;
    const u16* kbase = Kg + ((size_t)bh * BUDGET + krow) * 64 + kc * 16;
    const u16* vbase = VTg + ((size_t)bh * 64 + vrow) * BUDGET + vc * 16;
    v4u kr0 = *(const v4u*)(kbase + (size_t)t0 * 2048);
    v4u kr1 = *(const v4u*)(kbase + (size_t)t0 * 2048 + 8);
    v4u vr0 = *(const v4u*)(vbase + t0 * 32);
    v4u vr1 = *(const v4u*)(vbase + t0 * 32 + 8);
    int cur = 0;

    for (int t = t0; t < t1; ++t) {
        *(v4u*)(&Ks[cur][krow * 72 + kc * 16])     = kr0;
        *(v4u*)(&Ks[cur][krow * 72 + kc * 16 + 8]) = kr1;
        *(v4u*)(&Vs[cur][vrow * 40 + vc * 16])     = vr0;
        *(v4u*)(&Vs[cur][vrow * 40 + vc * 16 + 8]) = vr1;
        __syncthreads();
        // prefetch t+1 AFTER the barrier: its latency hides under this tile's compute
        if (t + 1 < t1) {
            kr0 = *(const v4u*)(kbase + (size_t)(t + 1) * 2048);
            kr1 = *(const v4u*)(kbase + (size_t)(t + 1) * 2048 + 8);
            vr0 = *(const v4u*)(vbase + (t + 1) * 32);
            vr1 = *(const v4u*)(vbase + (t + 1) * 32 + 8);
        }
        // S^T (32kv x 32q) = K * Q^T over d=64 (4 chunks of 16); s already in log2 units
        v16f s;
        #pragma unroll
        for (int e = 0; e < 16; ++e) s[e] = 0.f;
        v8s kf[4];
        #pragma unroll
        for (int c = 0; c < 4; ++c) kf[c] = *(const v8s*)(&Ks[cur][lq * 72 + c * 16 + G * 8]);
        __builtin_amdgcn_s_setprio(1);
        #pragma unroll
        for (int c = 0; c < 4; ++c)
            s = __builtin_amdgcn_mfma_f32_32x32x16_bf16(kf[c], Qf[c], s, 0, 0, 0);
        __builtin_amdgcn_s_setprio(0);
        // p = exp2(s) directly (no max subtraction; bounded logits, f32-safe)
        float p[16];
        #pragma unroll
        for (int e = 0; e < 16; ++e) p[e] = __builtin_amdgcn_exp2f(s[e]);
        float l0 = (p[0] + p[1]) + (p[2] + p[3]), l1 = (p[4] + p[5]) + (p[6] + p[7]);
        float l2 = (p[8] + p[9]) + (p[10] + p[11]), l3 = (p[12] + p[13]) + (p[14] + p[15]);
        lrun += (l0 + l1) + (l2 + l3);
        // P -> bf16 frags: reg r of s holds kv=(r&3)+8*(r>>2)+4G; dP[e]=(kv pair of r=2e,2e+1)
        u32 dP[8];
        #pragma unroll
        for (int e = 0; e < 8; ++e) dP[e] = pk2(p[2 * e], p[2 * e + 1]);
        auto r02 = __builtin_amdgcn_permlane32_swap(dP[0], dP[2], false, false);
        auto r13 = __builtin_amdgcn_permlane32_swap(dP[1], dP[3], false, false);
        auto r46 = __builtin_amdgcn_permlane32_swap(dP[4], dP[6], false, false);
        auto r57 = __builtin_amdgcn_permlane32_swap(dP[5], dP[7], false, false);
        const v8s P0 = mk8(r02[0], r13[0], r02[1], r13[1]);
        const v8s P1 = mk8(r46[0], r57[0], r46[1], r57[1]);
        // O^T (d x q) += V^T * P, two kv chunks of 16, two d chunks of 32
        v8s va0 = *(const v8s*)(&Vs[cur][lq * 40 + G * 8]);
        v8s vb0 = *(const v8s*)(&Vs[cur][(32 + lq) * 40 + G * 8]);
        v8s va1 = *(const v8s*)(&Vs[cur][lq * 40 + 16 + G * 8]);
        v8s vb1 = *(const v8s*)(&Vs[cur][(32 + lq) * 40 + 16 + G * 8]);
        __builtin_amdgcn_s_setprio(1);
        o0 = __builtin_amdgcn_mfma_f32_32x32x16_bf16(va0, P0, o0, 0, 0, 0);
        o1 = __builtin_amdgcn_mfma_f32_32x32x16_bf16(vb0, P0, o1, 0, 0, 0);
        o0 = __builtin_amdgcn_mfma_f32_32x32x16_bf16(va1, P1, o0, 0, 0, 0);
        o1 = __builtin_amdgcn_mfma_f32_32x32x16_bf16(vb1, P1, o1, 0, 0, 0);
        __builtin_amdgcn_s_setprio(0);
        cur ^= 1;
    }
    const float ltot = lrun + __shfl_xor(lrun, 32);
    const size_t base = (((size_t)(split * 32 + bh)) * 1024 + q) * 64;
    #pragma unroll
    for (int c = 0; c < 2; ++c) {
        #pragma unroll
        for (int rq = 0; rq < 4; ++rq) {
            union { u16 h[4]; v2u v; } pk_;
            #pragma unroll
            for (int e = 0; e < 4; ++e) pk_.h[e] = f2bf(c ? o1[4 * rq + e] : o0[4 * rq + e]);
            *(v2u*)(Opart + base + 32 * c + 8 * rq + 4 * G) = pk_.v;
        }
    }
    if (G == 0) {
        Lpart[(size_t)(split * 32 + bh) * 1024 + q] = ltot;
    }
}

// ---------------- K7: merge the 8 KV-splits (bf16 partials, common scale), write bf16 ----------------
__global__ void kmerge(const u16* __restrict__ Op, const float* __restrict__ Lp,
                       u16* __restrict__ attnbf) {
    const int idx = blockIdx.x * 256 + threadIdx.x;
    const int dq = idx & 15, q = (idx >> 4) & 1023, bh = idx >> 14;
    float den = 0.f;
    #pragma unroll
    for (int s = 0; s < NSPLIT; ++s) den += Lp[(size_t)(s * 32 + bh) * 1024 + q];
    const float rden = 1.0f / den;
    v4f acc; acc[0]=0.f; acc[1]=0.f; acc[2]=0.f; acc[3]=0.f;
    #pragma unroll
    for (int s = 0; s < NSPLIT; ++s) {
        union { u16 h[4]; v2u v; } a_;
        a_.v = *(const v2u*)(Op + ((((size_t)(s * 32 + bh)) * 1024 + q) * 64) + dq * 4);
        #pragma unroll
        for (int e = 0; e < 4; ++e) acc[e] += bf2f(a_.h[e]);
    }
    union { u16 h[4]; v2u v; } r_;
    #pragma unroll
    for (int e = 0; e < 4; ++e) r_.h[e] = f2bf(acc[e] * rden);
    const int bb = bh >> 4, h = bh & 15;
    *(v2u*)(attnbf + ((size_t)(bb * 1024 + q)) * 1024 + h * 64 + dq * 4) = r_.v;
}

// ---------------- K8: proj GEMM, 64x64 tile, BK=64, gl_lds staging (qkv-proven pattern) ----------------
__global__ __launch_bounds__(256) void gemm_proj64(
    const u16* __restrict__ A, const u16* __restrict__ Bm,
    const float* __restrict__ bias, float* __restrict__ Cout) {
    __shared__ u16 As[64 * 64];
    __shared__ u16 Bs[64 * 64];
    const int tid = threadIdx.x;
    const int l = tid & 63, w = tid >> 6;
    const int wm = w >> 1, wn = w & 1;
    const int by = blockIdx.x >> 4, bx = blockIdx.x & 15;
    v4f acc[2][2];
    #pragma unroll
    for (int a = 0; a < 2; ++a)
        #pragma unroll
        for (int b = 0; b < 2; ++b) { acc[a][b][0]=0.f; acc[a][b][1]=0.f; acc[a][b][2]=0.f; acc[a][b][3]=0.f; }

    const int lrow = l >> 3;                 // 0..7 within 8-row stripe
    const int lgr  = (l & 7) ^ lrow;         // pre-swizzled source granule
    const u16* pa = A  + ((size_t)(by * 64 + w * 16 + lrow)) * 1024 + lgr * 8;
    const u16* pb = Bm + ((size_t)(bx * 64 + w * 16 + lrow)) * 1024 + lgr * 8;

    for (int k0 = 0; k0 < 1024; k0 += 64) {
        if (k0) __syncthreads();
        #pragma unroll
        for (int j = 0; j < 2; ++j) {
            glds16(pa + j * 8192 + k0, &As[w * 1024 + j * 512]);
            glds16(pb + j * 8192 + k0, &Bs[w * 1024 + j * 512]);
        }
        __syncthreads();
        #pragma unroll
        for (int kc = 0; kc < 2; ++kc) {
            v8s af[2], bfr[2];
            #pragma unroll
            for (int mt = 0; mt < 2; ++mt) {
                const int R = wm * 32 + mt * 16 + (l & 15);
                const int g = (kc * 4 + (l >> 4)) ^ (R & 7);
                af[mt] = *(const v8s*)(&As[R * 64 + g * 8]);
            }
            #pragma unroll
            for (int nt = 0; nt < 2; ++nt) {
                const int R = wn * 32 + nt * 16 + (l & 15);
                const int g = (kc * 4 + (l >> 4)) ^ (R & 7);
                bfr[nt] = *(const v8s*)(&Bs[R * 64 + g * 8]);
            }
            #pragma unroll
            for (int mt = 0; mt < 2; ++mt)
                #pragma unroll
                for (int nt = 0; nt < 2; ++nt)
                    acc[mt][nt] = __builtin_amdgcn_mfma_f32_16x16x32_bf16(af[mt], bfr[nt], acc[mt][nt], 0, 0, 0);
        }
    }
    #pragma unroll
    for (int nt = 0; nt < 2; ++nt) {
        const int n = bx * 64 + wn * 32 + nt * 16 + (l & 15);
        const float bv = bias[n];
        #pragma unroll
        for (int mt = 0; mt < 2; ++mt)
            #pragma unroll
            for (int r = 0; r < 4; ++r) {
                const int m = by * 64 + wm * 32 + mt * 16 + (l >> 4) * 4 + r;
                Cout[(size_t)m * 1024 + n] = acc[mt][nt][r] + bv;
            }
    }
}

// ---------------- launcher ----------------
extern "C" void kernel_launch(void* const* d_in, const int* in_sizes, int n_in,
                              void* d_out, int out_size, void* d_ws, size_t ws_size,
                              hipStream_t stream) {
    const float* x      = (const float*)d_in[0];
    const float* past_k = (const float*)d_in[1];
    const float* past_v = (const float*)d_in[2];
    const float* imp    = (const float*)d_in[3];
    const float* qkv_w  = (const float*)d_in[4];
    const float* qkv_b  = (const float*)d_in[5];
    const float* proj_w = (const float*)d_in[6];
    const float* proj_b = (const float*)d_in[7];
    float* out = (float*)d_out;
    char* ws = (char*)d_ws;

    const size_t o_kg    = 0;                       // 16,384,000  (xcat @0: 8,388,608)
    const size_t o_vtg   = 16384000;                // 16,384,000  (wcat @8,388,608 -> 20,971,520)
    const size_t o_xcat  = 0;
    const size_t o_wcat  = 8388608;
    const size_t o_abf   = 0;                       //  4,194,304  (aliases Kg after attn)
    const size_t o_wproj = 32768000;                //  2,097,152
    const size_t o_qbf   = 34865152;                //  4,194,304
    const size_t o_opart = 39059456;                // 33,554,432 bf16 (aliases Kpart+Vnew, dead by attn)
    const size_t o_kpart = 39059456;                //  3 x 8,388,608 slices
    const size_t o_vnew  = 64225280;                //  8,388,608
    const size_t o_part  = 72613888;                //    278,528 (dead after kdiv)
    const size_t o_div   = 72900608;                //     61,440 (dead after kselect)
    const size_t o_keep  = 72962048;                //     27,904 (dead after kgather)
    const size_t o_lpart = 72613888;                //  1,048,576 (overlays part/div/keep post-kgather)
    const size_t total   = 74038528;
    if (ws_size < total) return;

    u16*   xcat  = (u16*)(ws + o_xcat);
    u16*   wcat  = (u16*)(ws + o_wcat);
    u16*   Kg    = (u16*)(ws + o_kg);
    u16*   VTg   = (u16*)(ws + o_vtg);
    u16*   wproj = (u16*)(ws + o_wproj);
    u16*   Qbf   = (u16*)(ws + o_qbf);
    float* Kpart = (float*)(ws + o_kpart);
    float* Vnew  = (float*)(ws + o_vnew);
    u16*   Opart = (u16*)(ws + o_opart);
    float* part  = (float*)(ws + o_part);
    float* divavg= (float*)(ws + o_div);
    int*   keep  = (int*)(ws + o_keep);
    float* Lpart = (float*)(ws + o_lpart);
    u16*   attnbf= (u16*)(ws + o_abf);

    prep<<<6144, 256, 0, stream>>>(x, qkv_w, proj_w, xcat, wcat, wproj);
    gemm_qkv<<<1280, 256, 0, stream>>>(xcat, wcat, qkv_b, Qbf, Vnew, Kpart);
    kmean<<<1088, 256, 0, stream>>>(past_k, Kpart, part);
    kdiv<<<480, 256, 0, stream>>>(past_k, part, divavg);
    kselect<<<2, 256, 0, stream>>>(divavg, imp, keep);
    kgather<<<2016, 256, 0, stream>>>(past_k, past_v, Kpart, Vnew, keep, Kg, VTg);
    attn<<<4096, 128, 0, stream>>>(Qbf, Kg, VTg, Opart, Lpart);
    kmerge<<<2048, 256, 0, stream>>>(Opart, Lpart, attnbf);
    gemm_proj64<<<512, 256, 0, stream>>>(attnbf, wproj, proj_b, out);
}

// Round 19
// 208.015 us; speedup vs baseline: 1.0267x; 1.0267x over previous
//
#include <hip/hip_runtime.h>
#include <hip/hip_bf16.h>

typedef unsigned short u16;
typedef unsigned int   u32;
typedef __attribute__((ext_vector_type(8)))  short v8s;
typedef __attribute__((ext_vector_type(4)))  float v4f;
typedef __attribute__((ext_vector_type(16))) float v16f;
typedef __attribute__((ext_vector_type(4)))  u32   v4u;
typedef __attribute__((ext_vector_type(2)))  u32   v2u;

#define B_      2
#define N_      1024
#define C_      1024
#define H_      16
#define BH_     32
#define PAST_   8192
#define BUDGET  4000
#define ANCHOR_ 512
#define NCAND   8704
#define NOLD    7680
#define KEEPN   3488
#define NSPLIT  4
#define KSLICE  2097152
#define QSCALE  0.18033688011112042f   /* 0.125 * log2(e) : softmax in log2 domain */

__device__ __forceinline__ u16 f2bf(float f) {
    u32 u = __float_as_uint(f);
    u32 r = u + 0x7fffu + ((u >> 16) & 1u);
    return (u16)(r >> 16);
}
__device__ __forceinline__ float bf2f(u16 h) {
    return __uint_as_float(((u32)h) << 16);
}
__device__ __forceinline__ u32 pk2(float a, float b) {
    __hip_bfloat162 t = __float22bfloat162_rn(float2{a, b});
    u32 r; __builtin_memcpy(&r, &t, 4); return r;
}
__device__ __forceinline__ v8s mk8(u32 a, u32 b, u32 c, u32 d) {
    v4u t; t[0] = a; t[1] = b; t[2] = c; t[3] = d;
    return __builtin_bit_cast(v8s, t);
}
__device__ __forceinline__ void glds16(const u16* g, u16* l) {
    __builtin_amdgcn_global_load_lds((const __attribute__((address_space(1))) u32*)g,
                                     (__attribute__((address_space(3))) u32*)l, 16, 0, 0);
}

// ---------------- K0: prep (hi/lo split, DEDUP'd concat operands), 4 elems/thread ----------------
// xcat (2048 x 2048) = [x_hi | x_lo]; wcat (3072 x 2048) = [w_hi | w_lo]
__global__ void prep(const float* __restrict__ x, const float* __restrict__ qw,
                     const float* __restrict__ pw, u16* __restrict__ xcat,
                     u16* __restrict__ wcat, u16* __restrict__ wpbf) {
    const int i = (blockIdx.x * 256 + threadIdx.x) << 2;
    const int NX = 2048 * 1024, NW = 3072 * 1024;
    if (i < NX) {
        const v4f v = *(const v4f*)(x + i);
        union { u16 h[4]; v2u u; } hi, lo;
        #pragma unroll
        for (int e = 0; e < 4; ++e) {
            hi.h[e] = f2bf(v[e]);
            lo.h[e] = f2bf(v[e] - bf2f(hi.h[e]));
        }
        const int m = i >> 10, k = i & 1023;
        u16* p = xcat + (size_t)m * 2048 + k;
        *(v2u*)p = hi.u; *(v2u*)(p + 1024) = lo.u;
    } else if (i < NX + NW) {
        const int j = i - NX;
        const v4f v = *(const v4f*)(qw + j);
        union { u16 h[4]; v2u u; } hi, lo;
        #pragma unroll
        for (int e = 0; e < 4; ++e) {
            hi.h[e] = f2bf(v[e]);
            lo.h[e] = f2bf(v[e] - bf2f(hi.h[e]));
        }
        const int n = j >> 10, k = j & 1023;
        u16* p = wcat + (size_t)n * 2048 + k;
        *(v2u*)p = hi.u; *(v2u*)(p + 1024) = lo.u;
    } else {
        const int j = i - NX - NW;
        const v4f v = *(const v4f*)(pw + j);
        union { u16 h[4]; v2u u; } hv;
        #pragma unroll
        for (int e = 0; e < 4; ++e) hv.h[e] = f2bf(v[e]);
        *(v2u*)(wpbf + j) = hv.u;
    }
}

// ---------------- K1: QKV GEMM, uniform split-K, 64x128 tile, BK=64 ----------------
// grid 1280: Q(256), V(256), K(3x256 slices). Per-operand column base selects
// the hi/lo slice: s0 = x_hi*w_hi, s1 = x_hi*w_lo, s2 = x_lo*w_hi.
// global_load_lds staging, XOR-swizzled SOURCE granule, XOR'd reads -> conflict-free.
__global__ __launch_bounds__(256) void gemm_qkv(
    const u16* __restrict__ A, const u16* __restrict__ Bm,
    const float* __restrict__ bias,
    u16* __restrict__ Qbf, float* __restrict__ Vnew, float* __restrict__ Kpart) {
    __shared__ u16 As[64 * 64];
    __shared__ u16 Bs[128 * 64];
    const int tid = threadIdx.x;
    const int l = tid & 63, w = tid >> 6;
    const int wm = w >> 1, wn = w & 1;
    const int bid = blockIdx.x;
    int tsel, by, bx, s;
    if (bid < 256)      { tsel = 0; s = 0; const int r = bid;       by = r >> 3; bx = r & 7; }
    else if (bid < 512) { tsel = 2; s = 0; const int r = bid - 256; by = r >> 3; bx = r & 7; }
    else                { const int rr = bid - 512; s = rr >> 8; const int r = rr & 255;
                          tsel = 1; by = r >> 3; bx = r & 7; }
    const int ksA = (s == 2) ? 1024 : 0;   // x_lo only for slice 2
    const int ksB = (s == 1) ? 1024 : 0;   // w_lo only for slice 1
    const int nbase = tsel * 1024 + bx * 128;

    v4f acc[2][4];
    #pragma unroll
    for (int a = 0; a < 2; ++a)
        #pragma unroll
        for (int b = 0; b < 4; ++b) { acc[a][b][0]=0.f; acc[a][b][1]=0.f; acc[a][b][2]=0.f; acc[a][b][3]=0.f; }

    const int lrow = l >> 3;                 // 0..7 within 8-row stripe
    const int lgr  = (l & 7) ^ lrow;         // pre-swizzled source granule
    const u16* pa = A  + ((size_t)(by * 64 + w * 16 + lrow)) * 2048 + ksA + lgr * 8;
    const u16* pb = Bm + ((size_t)(nbase + w * 32 + lrow))   * 2048 + ksB + lgr * 8;

    for (int k0 = 0; k0 < 1024; k0 += 64) {
        if (k0) __syncthreads();
        #pragma unroll
        for (int j = 0; j < 2; ++j)
            glds16(pa + j * 16384 + k0, &As[w * 1024 + j * 512]);
        #pragma unroll
        for (int j = 0; j < 4; ++j)
            glds16(pb + j * 16384 + k0, &Bs[w * 2048 + j * 512]);
        __syncthreads();
        #pragma unroll
        for (int kc = 0; kc < 2; ++kc) {
            v8s af[2], bfr[4];
            #pragma unroll
            for (int mt = 0; mt < 2; ++mt) {
                const int R = wm * 32 + mt * 16 + (l & 15);
                const int g = (kc * 4 + (l >> 4)) ^ (R & 7);
                af[mt] = *(const v8s*)(&As[R * 64 + g * 8]);
            }
            #pragma unroll
            for (int nt = 0; nt < 4; ++nt) {
                const int R = wn * 64 + nt * 16 + (l & 15);
                const int g = (kc * 4 + (l >> 4)) ^ (R & 7);
                bfr[nt] = *(const v8s*)(&Bs[R * 64 + g * 8]);
            }
            #pragma unroll
            for (int mt = 0; mt < 2; ++mt)
                #pragma unroll
                for (int nt = 0; nt < 4; ++nt)
                    acc[mt][nt] = __builtin_amdgcn_mfma_f32_16x16x32_bf16(af[mt], bfr[nt], acc[mt][nt], 0, 0, 0);
        }
    }
    // epilogue: head-layout (bb*16+hh, nn, dd)
    #pragma unroll
    for (int nt = 0; nt < 4; ++nt) {
        const int nl = bx * 128 + wn * 64 + nt * 16 + (l & 15);   // [0,1024)
        const int hh = nl >> 6, dd = nl & 63;
        const float bv = bias[tsel * 1024 + nl];
        #pragma unroll
        for (int mt = 0; mt < 2; ++mt)
            #pragma unroll
            for (int r = 0; r < 4; ++r) {
                const int m = by * 64 + wm * 32 + mt * 16 + (l >> 4) * 4 + r;
                const int bb = m >> 10, nn = m & 1023;
                const size_t o = (((size_t)(bb * 16 + hh)) * 1024 + nn) * 64 + dd;
                if (tsel == 0)      Qbf[o] = f2bf((acc[mt][nt][r] + bv) * QSCALE);
                else if (tsel == 2) Vnew[o] = acc[mt][nt][r] + bv;
                else                Kpart[(size_t)s * KSLICE + o] = acc[mt][nt][r] + (s == 0 ? bv : 0.f);
            }
    }
}

// ---------------- K2: normalized-row sums; K-new rows summed from 3 slices inline ----------------
__global__ __launch_bounds__(256) void kmean(const float* __restrict__ past_k,
                                             const float* __restrict__ Kp,
                                             float* __restrict__ part) {
    __shared__ float Asum[4][64];
    const int blk = blockIdx.x, tid = threadIdx.x;
    const int bh = blk / 34, seg = blk % 34;
    const int l = tid & 63, w = tid >> 6;
    const int rr = l >> 4, dd = l & 15;
    v4f acc; acc[0]=0.f; acc[1]=0.f; acc[2]=0.f; acc[3]=0.f;
    const int base = seg * 256 + w * 64;
    for (int q4 = 0; q4 < 64; q4 += 4) {
        const int i = base + q4 + rr;
        v4f v;
        if (i < NOLD) {
            v = *(const v4f*)(past_k + (((size_t)bh * PAST_) + ANCHOR_ + i) * 64 + dd * 4);
        } else {
            const float* r0 = Kp + (((size_t)bh * N_) + (i - NOLD)) * 64 + dd * 4;
            v4f a = *(const v4f*)r0;
            v4f b = *(const v4f*)(r0 + KSLICE);
            v4f c = *(const v4f*)(r0 + 2 * KSLICE);
            #pragma unroll
            for (int e = 0; e < 4; ++e) v[e] = (a[e] + b[e]) + c[e];
        }
        float ss = v[0]*v[0] + v[1]*v[1] + v[2]*v[2] + v[3]*v[3];
        ss += __shfl_xor(ss, 1); ss += __shfl_xor(ss, 2);
        ss += __shfl_xor(ss, 4); ss += __shfl_xor(ss, 8);
        const float rn = 1.0f / fmaxf(sqrtf(ss), 1e-12f);
        acc[0] += v[0]*rn; acc[1] += v[1]*rn; acc[2] += v[2]*rn; acc[3] += v[3]*rn;
    }
    #pragma unroll
    for (int e = 0; e < 4; ++e) { acc[e] += __shfl_xor(acc[e], 16); acc[e] += __shfl_xor(acc[e], 32); }
    if (l < 16) *(v4f*)(&Asum[w][dd * 4]) = acc;
    __syncthreads();
    if (tid < 64) {
        float s = Asum[0][tid] + Asum[1][tid] + Asum[2][tid] + Asum[3][tid];
        part[((size_t)seg * BH_ + bh) * 64 + tid] = s;
    }
}

// ---------------- K3: baseline / div_avg (part-reduce fused in) ----------------
__global__ __launch_bounds__(256) void kdiv(const float* __restrict__ past_k,
                                            const float* __restrict__ part,
                                            float* __restrict__ divavg) {
    __shared__ float MV[1024];
    const int blk = blockIdx.x, tid = threadIdx.x;
    const int b = blk / 240, ib = blk % 240;
    for (int j = tid; j < 1024; j += 256) {
        const float* pp = part + b * 1024 + j;
        float s = 0.f;
        #pragma unroll
        for (int g = 0; g < 34; ++g) s += pp[(size_t)g * 2048];
        MV[j] = s / 8704.0f;
    }
    __syncthreads();
    const int l = tid & 63, w = tid >> 6;
    const int rr = l >> 4, dd = l & 15;
    for (int ii = 0; ii < 8; ++ii) {
        const int i = ib * 32 + w * 8 + ii;
        float accv = 0.f;
        #pragma unroll
        for (int hq = 0; hq < 4; ++hq) {
            const int h = hq * 4 + rr;
            const v4f v  = *(const v4f*)(past_k + (((size_t)(b * 16 + h)) * PAST_ + ANCHOR_ + i) * 64 + dd * 4);
            const v4f mv = *(const v4f*)(&MV[h * 64 + dd * 4]);
            float ss = v[0]*v[0] + v[1]*v[1] + v[2]*v[2] + v[3]*v[3];
            float dp = v[0]*mv[0] + v[1]*mv[1] + v[2]*mv[2] + v[3]*mv[3];
            ss += __shfl_xor(ss, 1); dp += __shfl_xor(dp, 1);
            ss += __shfl_xor(ss, 2); dp += __shfl_xor(dp, 2);
            ss += __shfl_xor(ss, 4); dp += __shfl_xor(dp, 4);
            ss += __shfl_xor(ss, 8); dp += __shfl_xor(dp, 8);
            accv += 1.0f - dp / fmaxf(sqrtf(ss), 1e-12f);
        }
        accv += __shfl_xor(accv, 16); accv += __shfl_xor(accv, 32);
        if (l == 0) divavg[(size_t)b * NOLD + i] = accv / 16.0f;
    }
}

// ---------------- K4: per-batch top-k (register-resident; shfl-scan compaction) ----------------
__global__ __launch_bounds__(256) void kselect(const float* __restrict__ divavg,
                                               const float* __restrict__ imp,
                                               int* __restrict__ keep) {
    __shared__ float comb[NCAND];
    __shared__ float red[16];
    __shared__ u32 scnt[2][4];
    __shared__ u32 wg_[4], we_[4];
    const int b = blockIdx.x, tid = threadIdx.x;
    const int l = tid & 63, w = tid >> 6;

    float mn = 1e30f, mx = -1e30f;
    for (int i = tid; i < NOLD; i += 256) { float v = divavg[b * NOLD + i]; mn = fminf(mn, v); mx = fmaxf(mx, v); }
    #pragma unroll
    for (int d = 1; d < 64; d <<= 1) { mn = fminf(mn, __shfl_xor(mn, d)); mx = fmaxf(mx, __shfl_xor(mx, d)); }
    if (l == 0) { red[w] = mn; red[4 + w] = mx; }
    float mn2 = 1e30f, mx2 = -1e30f;
    for (int i = tid; i < N_; i += 256) { float v = imp[b * N_ + i]; mn2 = fminf(mn2, v); mx2 = fmaxf(mx2, v); }
    #pragma unroll
    for (int d = 1; d < 64; d <<= 1) { mn2 = fminf(mn2, __shfl_xor(mn2, d)); mx2 = fmaxf(mx2, __shfl_xor(mx2, d)); }
    if (l == 0) { red[8 + w] = mn2; red[12 + w] = mx2; }
    __syncthreads();
    const float omin = fminf(fminf(red[0], red[1]), fminf(red[2], red[3]));
    const float omax = fmaxf(fmaxf(red[4], red[5]), fmaxf(red[6], red[7]));
    const float imin = fminf(fminf(red[8], red[9]), fminf(red[10], red[11]));
    const float imax = fmaxf(fmaxf(red[12], red[13]), fmaxf(red[14], red[15]));
    const float oden = omax - omin + 1e-8f, iden = imax - imin + 1e-8f;
    for (int i = tid; i < NCAND; i += 256)
        comb[i] = (i < NOLD) ? 0.5f * ((divavg[b * NOLD + i] - omin) / oden)
                             : 0.5f * ((imp[b * N_ + i - NOLD] - imin) / iden);
    __syncthreads();
    u32 fu[34];
    const int i0 = tid * 34;
    #pragma unroll
    for (int j = 0; j < 34; ++j) fu[j] = __float_as_uint(comb[i0 + j]);
    // bisection for tau = KEEPN-th largest (uint order; comb in [0, 0.5) so hi=0x3F000000 safe)
    u32 lo = 0, hi = 0x3F000000u;
    int it = 0;
    while (lo < hi) {
        const u32 mid = lo + ((hi - lo) >> 1);
        u32 c = 0;
        #pragma unroll
        for (int j = 0; j < 34; ++j) c += (fu[j] > mid) ? 1u : 0u;
        c += __shfl_xor(c, 1); c += __shfl_xor(c, 2); c += __shfl_xor(c, 4);
        c += __shfl_xor(c, 8); c += __shfl_xor(c, 16); c += __shfl_xor(c, 32);
        if (l == 0) scnt[it & 1][w] = c;
        __syncthreads();
        const u32 total = scnt[it & 1][0] + scnt[it & 1][1] + scnt[it & 1][2] + scnt[it & 1][3];
        if (total < KEEPN) hi = mid; else lo = mid + 1;
        ++it;
    }
    const u32 tau = lo;
    u32 ng = 0, ne = 0;
    #pragma unroll
    for (int j = 0; j < 34; ++j) { ng += (fu[j] > tau); ne += (fu[j] == tau); }
    // exact exclusive prefix via wave shfl-scan + per-wave offsets
    u32 gi = ng, ei = ne;
    #pragma unroll
    for (int d = 1; d < 64; d <<= 1) {
        u32 tg = __shfl_up(gi, d), te = __shfl_up(ei, d);
        if (l >= d) { gi += tg; ei += te; }
    }
    if (l == 63) { wg_[w] = gi; we_[w] = ei; }
    __syncthreads();
    u32 offg = 0, offe = 0, totg = 0;
    #pragma unroll
    for (int ww = 0; ww < 4; ++ww) {
        if (ww < w) { offg += wg_[ww]; offe += we_[ww]; }
        totg += wg_[ww];
    }
    const u32 need = KEEPN - totg;
    u32 g = offg + gi - ng;
    u32 e = offe + ei - ne;
    #pragma unroll
    for (int j = 0; j < 34; ++j) {
        const u32 u = fu[j];
        const bool kg = u > tau;
        const bool ke = (u == tau) && (e < need);
        if (kg || ke) keep[b * KEEPN + (g + (e < need ? e : need))] = 512 + i0 + j;
        g += kg ? 1u : 0u; e += (u == tau) ? 1u : 0u;
    }
}

// ---------------- K5: gather kept K/V -> bf16 Kg (row-major), VTg (transposed) ----------------
__global__ __launch_bounds__(256) void kgather(const float* __restrict__ past_k,
    const float* __restrict__ past_v, const float* __restrict__ Kp,
    const float* __restrict__ Vnew, const int* __restrict__ keep,
    u16* __restrict__ Kg, u16* __restrict__ VTg) {
    __shared__ float VL[64][65];
    const int blk = blockIdx.x, tid = threadIdx.x;
    const int bh = blk / 63, jb = blk % 63;
    const int b = bh >> 4;
    const int jj = tid >> 2, cc = tid & 3;
    const int j = jb * 64 + jj;
    if (j < BUDGET) {
        const int row = (j < ANCHOR_) ? j : keep[b * KEEPN + (j - ANCHOR_)];
        union { u16 h[16]; v4u v[2]; } pk_;
        if (row < PAST_) {
            const size_t o = ((size_t)bh * PAST_ + row) * 64;
            const float* ks = past_k + o;
            const float* vs = past_v + o;
            #pragma unroll
            for (int q4 = 0; q4 < 4; ++q4) {
                v4f kv = *(const v4f*)(ks + cc * 16 + q4 * 4);
                v4f vv = *(const v4f*)(vs + cc * 16 + q4 * 4);
                #pragma unroll
                for (int e = 0; e < 4; ++e) {
                    pk_.h[q4 * 4 + e] = f2bf(kv[e]);
                    VL[jj][cc * 16 + q4 * 4 + e] = vv[e];
                }
            }
        } else {
            const size_t o = ((size_t)bh * N_ + (row - PAST_)) * 64;
            const float* k0 = Kp + o;
            const float* vs = Vnew + o;
            #pragma unroll
            for (int q4 = 0; q4 < 4; ++q4) {
                v4f a = *(const v4f*)(k0 + cc * 16 + q4 * 4);
                v4f bb2 = *(const v4f*)(k0 + KSLICE + cc * 16 + q4 * 4);
                v4f c = *(const v4f*)(k0 + 2 * KSLICE + cc * 16 + q4 * 4);
                v4f vv = *(const v4f*)(vs + cc * 16 + q4 * 4);
                #pragma unroll
                for (int e = 0; e < 4; ++e) {
                    pk_.h[q4 * 4 + e] = f2bf((a[e] + bb2[e]) + c[e]);
                    VL[jj][cc * 16 + q4 * 4 + e] = vv[e];
                }
            }
        }
        v4u* kout = (v4u*)(Kg + ((size_t)bh * BUDGET + j) * 64 + cc * 16);
        kout[0] = pk_.v[0]; kout[1] = pk_.v[1];
    }
    __syncthreads();
    const int d = tid >> 2, c4 = tid & 3;
    const int jc = c4 * 16;
    if (jb * 64 + jc < BUDGET) {
        union { u16 h[16]; v4u v[2]; } pv_;
        #pragma unroll
        for (int t2 = 0; t2 < 16; ++t2) pv_.h[t2] = f2bf(VL[jc + t2][d]);
        v4u* vout = (v4u*)(VTg + ((size_t)bh * 64 + d) * BUDGET + jb * 64 + jc);
        vout[0] = pv_.v[0]; vout[1] = pv_.v[1];
    }
}

// ---------------- K6: flash attention, swapped QK^T, 32x32x16 MFMA (r12-proven) ----------------
// grid 2048 x 128thr: bh(32) x qblk(16) x split(4), 2 waves/wg, each wave owns 32 q.
// NO-MAX softmax (bounded log2-domain logits). Reg-staged K (stride-72 LDS) +
// prefetch AFTER the barrier (full compute phase covers latency). Raw v_exp_f32.
// Double-buffered LDS, 1 barrier/tile, permlane32 P-frags, setprio, XCD swizzle.
__global__ __launch_bounds__(128, 4) void attn(const u16* __restrict__ Qbf,
    const u16* __restrict__ Kg, const u16* __restrict__ VTg,
    u16* __restrict__ Opart, float* __restrict__ Lpart) {
    __shared__ u16 Ks[2][32 * 72];
    __shared__ u16 Vs[2][64 * 40];
    const int tid = threadIdx.x;
    const int l = tid & 63, w = tid >> 6;
    const int G = l >> 5, lq = l & 31;
    const int bid = ((blockIdx.x & 7) << 8) | (blockIdx.x >> 3);
    const int bh = bid >> 6, rem = bid & 63;
    const int split = rem & 3, qblk = rem >> 2;
    const int q = qblk * 64 + w * 32 + lq;
    const int t0 = split * 32;
    const int t1 = (split == 3) ? 125 : (t0 + 32);

    v8s Qf[4];
    const v8s* qp = (const v8s*)(Qbf + ((size_t)(bh * 1024 + q)) * 64);
    #pragma unroll
    for (int c = 0; c < 4; ++c) Qf[c] = qp[c * 2 + G];

    v16f o0, o1;
    #pragma unroll
    for (int e = 0; e < 16; ++e) { o0[e] = 0.f; o1[e] = 0.f; }
    float lrun = 0.f;

    const int krow = tid >> 2, kc = tid & 3;
    const int vrow = tid >> 1, vc = tid & 1;
    const u16* kbase = Kg + ((size_t)bh * BUDGET + krow) * 64 + kc * 16;
    const u16* vbase = VTg + ((size_t)bh * 64 + vrow) * BUDGET + vc * 16;
    v4u kr0 = *(const v4u*)(kbase + (size_t)t0 * 2048);
    v4u kr1 = *(const v4u*)(kbase + (size_t)t0 * 2048 + 8);
    v4u vr0 = *(const v4u*)(vbase + t0 * 32);
    v4u vr1 = *(const v4u*)(vbase + t0 * 32 + 8);
    int cur = 0;

    for (int t = t0; t < t1; ++t) {
        *(v4u*)(&Ks[cur][krow * 72 + kc * 16])     = kr0;
        *(v4u*)(&Ks[cur][krow * 72 + kc * 16 + 8]) = kr1;
        *(v4u*)(&Vs[cur][vrow * 40 + vc * 16])     = vr0;
        *(v4u*)(&Vs[cur][vrow * 40 + vc * 16 + 8]) = vr1;
        __syncthreads();
        // prefetch t+1 AFTER the barrier: its latency hides under this tile's compute
        if (t + 1 < t1) {
            kr0 = *(const v4u*)(kbase + (size_t)(t + 1) * 2048);
            kr1 = *(const v4u*)(kbase + (size_t)(t + 1) * 2048 + 8);
            vr0 = *(const v4u*)(vbase + (t + 1) * 32);
            vr1 = *(const v4u*)(vbase + (t + 1) * 32 + 8);
        }
        // S^T (32kv x 32q) = K * Q^T over d=64 (4 chunks of 16); s already in log2 units
        v16f s;
        #pragma unroll
        for (int e = 0; e < 16; ++e) s[e] = 0.f;
        v8s kf[4];
        #pragma unroll
        for (int c = 0; c < 4; ++c) kf[c] = *(const v8s*)(&Ks[cur][lq * 72 + c * 16 + G * 8]);
        __builtin_amdgcn_s_setprio(1);
        #pragma unroll
        for (int c = 0; c < 4; ++c)
            s = __builtin_amdgcn_mfma_f32_32x32x16_bf16(kf[c], Qf[c], s, 0, 0, 0);
        __builtin_amdgcn_s_setprio(0);
        // p = exp2(s) directly (no max subtraction; bounded logits, f32-safe);
        // raw v_exp_f32 (libm exp2f adds a subnormal fixup we can't hit)
        float p[16];
        #pragma unroll
        for (int e = 0; e < 16; ++e) p[e] = __builtin_amdgcn_exp2f(s[e]);
        float l0 = (p[0] + p[1]) + (p[2] + p[3]), l1 = (p[4] + p[5]) + (p[6] + p[7]);
        float l2 = (p[8] + p[9]) + (p[10] + p[11]), l3 = (p[12] + p[13]) + (p[14] + p[15]);
        lrun += (l0 + l1) + (l2 + l3);
        // P -> bf16 frags: reg r of s holds kv=(r&3)+8*(r>>2)+4G; dP[e]=(kv pair of r=2e,2e+1)
        u32 dP[8];
        #pragma unroll
        for (int e = 0; e < 8; ++e) dP[e] = pk2(p[2 * e], p[2 * e + 1]);
        // B-frag word w needs kv pair (8G+2w, 8G+2w+1): one permlane32_swap fills two words
        auto r02 = __builtin_amdgcn_permlane32_swap(dP[0], dP[2], false, false);
        auto r13 = __builtin_amdgcn_permlane32_swap(dP[1], dP[3], false, false);
        auto r46 = __builtin_amdgcn_permlane32_swap(dP[4], dP[6], false, false);
        auto r57 = __builtin_amdgcn_permlane32_swap(dP[5], dP[7], false, false);
        const v8s P0 = mk8(r02[0], r13[0], r02[1], r13[1]);
        const v8s P1 = mk8(r46[0], r57[0], r46[1], r57[1]);
        // O^T (d x q) += V^T * P, two kv chunks of 16, two d chunks of 32
        v8s va0 = *(const v8s*)(&Vs[cur][lq * 40 + G * 8]);
        v8s vb0 = *(const v8s*)(&Vs[cur][(32 + lq) * 40 + G * 8]);
        v8s va1 = *(const v8s*)(&Vs[cur][lq * 40 + 16 + G * 8]);
        v8s vb1 = *(const v8s*)(&Vs[cur][(32 + lq) * 40 + 16 + G * 8]);
        __builtin_amdgcn_s_setprio(1);
        o0 = __builtin_amdgcn_mfma_f32_32x32x16_bf16(va0, P0, o0, 0, 0, 0);
        o1 = __builtin_amdgcn_mfma_f32_32x32x16_bf16(vb0, P0, o1, 0, 0, 0);
        o0 = __builtin_amdgcn_mfma_f32_32x32x16_bf16(va1, P1, o0, 0, 0, 0);
        o1 = __builtin_amdgcn_mfma_f32_32x32x16_bf16(vb1, P1, o1, 0, 0, 0);
        __builtin_amdgcn_s_setprio(0);
        cur ^= 1;
    }
    const float ltot = lrun + __shfl_xor(lrun, 32);
    const size_t base = (((size_t)(split * 32 + bh)) * 1024 + q) * 64;
    #pragma unroll
    for (int c = 0; c < 2; ++c) {
        #pragma unroll
        for (int rq = 0; rq < 4; ++rq) {
            union { u16 h[4]; v2u v; } pk_;
            #pragma unroll
            for (int e = 0; e < 4; ++e) pk_.h[e] = f2bf(c ? o1[4 * rq + e] : o0[4 * rq + e]);
            *(v2u*)(Opart + base + 32 * c + 8 * rq + 4 * G) = pk_.v;
        }
    }
    if (G == 0) {
        Lpart[(size_t)(split * 32 + bh) * 1024 + q] = ltot;
    }
}

// ---------------- K7: merge the 4 KV-splits (bf16 partials, common scale), write bf16 ----------------
__global__ void kmerge(const u16* __restrict__ Op, const float* __restrict__ Lp,
                       u16* __restrict__ attnbf) {
    const int idx = blockIdx.x * 256 + threadIdx.x;
    const int dq = idx & 15, q = (idx >> 4) & 1023, bh = idx >> 14;
    float den = 0.f;
    #pragma unroll
    for (int s = 0; s < NSPLIT; ++s) den += Lp[(size_t)(s * 32 + bh) * 1024 + q];
    const float rden = 1.0f / den;
    v4f acc; acc[0]=0.f; acc[1]=0.f; acc[2]=0.f; acc[3]=0.f;
    #pragma unroll
    for (int s = 0; s < NSPLIT; ++s) {
        union { u16 h[4]; v2u v; } a_;
        a_.v = *(const v2u*)(Op + ((((size_t)(s * 32 + bh)) * 1024 + q) * 64) + dq * 4);
        #pragma unroll
        for (int e = 0; e < 4; ++e) acc[e] += bf2f(a_.h[e]);
    }
    union { u16 h[4]; v2u v; } r_;
    #pragma unroll
    for (int e = 0; e < 4; ++e) r_.h[e] = f2bf(acc[e] * rden);
    const int bb = bh >> 4, h = bh & 15;
    *(v2u*)(attnbf + ((size_t)(bb * 1024 + q)) * 1024 + h * 64 + dq * 4) = r_.v;
}

// ---------------- K8: proj GEMM, 64x64 tile, BK=64, gl_lds staging (qkv-proven pattern) ----------------
__global__ __launch_bounds__(256) void gemm_proj64(
    const u16* __restrict__ A, const u16* __restrict__ Bm,
    const float* __restrict__ bias, float* __restrict__ Cout) {
    __shared__ u16 As[64 * 64];
    __shared__ u16 Bs[64 * 64];
    const int tid = threadIdx.x;
    const int l = tid & 63, w = tid >> 6;
    const int wm = w >> 1, wn = w & 1;
    const int by = blockIdx.x >> 4, bx = blockIdx.x & 15;
    v4f acc[2][2];
    #pragma unroll
    for (int a = 0; a < 2; ++a)
        #pragma unroll
        for (int b = 0; b < 2; ++b) { acc[a][b][0]=0.f; acc[a][b][1]=0.f; acc[a][b][2]=0.f; acc[a][b][3]=0.f; }

    const int lrow = l >> 3;                 // 0..7 within 8-row stripe
    const int lgr  = (l & 7) ^ lrow;         // pre-swizzled source granule
    const u16* pa = A  + ((size_t)(by * 64 + w * 16 + lrow)) * 1024 + lgr * 8;
    const u16* pb = Bm + ((size_t)(bx * 64 + w * 16 + lrow)) * 1024 + lgr * 8;

    for (int k0 = 0; k0 < 1024; k0 += 64) {
        if (k0) __syncthreads();
        #pragma unroll
        for (int j = 0; j < 2; ++j) {
            glds16(pa + j * 8192 + k0, &As[w * 1024 + j * 512]);
            glds16(pb + j * 8192 + k0, &Bs[w * 1024 + j * 512]);
        }
        __syncthreads();
        #pragma unroll
        for (int kc = 0; kc < 2; ++kc) {
            v8s af[2], bfr[2];
            #pragma unroll
            for (int mt = 0; mt < 2; ++mt) {
                const int R = wm * 32 + mt * 16 + (l & 15);
                const int g = (kc * 4 + (l >> 4)) ^ (R & 7);
                af[mt] = *(const v8s*)(&As[R * 64 + g * 8]);
            }
            #pragma unroll
            for (int nt = 0; nt < 2; ++nt) {
                const int R = wn * 32 + nt * 16 + (l & 15);
                const int g = (kc * 4 + (l >> 4)) ^ (R & 7);
                bfr[nt] = *(const v8s*)(&Bs[R * 64 + g * 8]);
            }
            #pragma unroll
            for (int mt = 0; mt < 2; ++mt)
                #pragma unroll
                for (int nt = 0; nt < 2; ++nt)
                    acc[mt][nt] = __builtin_amdgcn_mfma_f32_16x16x32_bf16(af[mt], bfr[nt], acc[mt][nt], 0, 0, 0);
        }
    }
    #pragma unroll
    for (int nt = 0; nt < 2; ++nt) {
        const int n = bx * 64 + wn * 32 + nt * 16 + (l & 15);
        const float bv = bias[n];
        #pragma unroll
        for (int mt = 0; mt < 2; ++mt)
            #pragma unroll
            for (int r = 0; r < 4; ++r) {
                const int m = by * 64 + wm * 32 + mt * 16 + (l >> 4) * 4 + r;
                Cout[(size_t)m * 1024 + n] = acc[mt][nt][r] + bv;
            }
    }
}

// ---------------- launcher ----------------
extern "C" void kernel_launch(void* const* d_in, const int* in_sizes, int n_in,
                              void* d_out, int out_size, void* d_ws, size_t ws_size,
                              hipStream_t stream) {
    const float* x      = (const float*)d_in[0];
    const float* past_k = (const float*)d_in[1];
    const float* past_v = (const float*)d_in[2];
    const float* imp    = (const float*)d_in[3];
    const float* qkv_w  = (const float*)d_in[4];
    const float* qkv_b  = (const float*)d_in[5];
    const float* proj_w = (const float*)d_in[6];
    const float* proj_b = (const float*)d_in[7];
    float* out = (float*)d_out;
    char* ws = (char*)d_ws;

    const size_t o_kg    = 0;                       // 16,384,000  (xcat @0: 8,388,608)
    const size_t o_vtg   = 16384000;                // 16,384,000  (wcat @8,388,608 -> 20,971,520)
    const size_t o_xcat  = 0;
    const size_t o_wcat  = 8388608;
    const size_t o_abf   = 0;                       //  4,194,304  (aliases Kg after attn)
    const size_t o_wproj = 32768000;                //  2,097,152
    const size_t o_qbf   = 34865152;                //  4,194,304
    const size_t o_opart = 39059456;                // 16,777,216 (bf16; region also holds Kpart)
    const size_t o_kpart = 39059456;                //  3 x 8,388,608 slices
    const size_t o_vnew  = 64225280;                //  8,388,608
    const size_t o_part  = 72613888;                //    278,528
    const size_t o_div   = 72900608;                //     61,440
    const size_t o_keep  = 72962048;                //     27,904
    const size_t o_lpart = 73514240;                //    524,288
    const size_t total   = 74038528;
    if (ws_size < total) return;

    u16*   xcat  = (u16*)(ws + o_xcat);
    u16*   wcat  = (u16*)(ws + o_wcat);
    u16*   Kg    = (u16*)(ws + o_kg);
    u16*   VTg   = (u16*)(ws + o_vtg);
    u16*   wproj = (u16*)(ws + o_wproj);
    u16*   Qbf   = (u16*)(ws + o_qbf);
    float* Kpart = (float*)(ws + o_kpart);
    float* Vnew  = (float*)(ws + o_vnew);
    u16*   Opart = (u16*)(ws + o_opart);
    float* part  = (float*)(ws + o_part);
    float* divavg= (float*)(ws + o_div);
    int*   keep  = (int*)(ws + o_keep);
    float* Lpart = (float*)(ws + o_lpart);
    u16*   attnbf= (u16*)(ws + o_abf);

    prep<<<6144, 256, 0, stream>>>(x, qkv_w, proj_w, xcat, wcat, wproj);
    gemm_qkv<<<1280, 256, 0, stream>>>(xcat, wcat, qkv_b, Qbf, Vnew, Kpart);
    kmean<<<1088, 256, 0, stream>>>(past_k, Kpart, part);
    kdiv<<<480, 256, 0, stream>>>(past_k, part, divavg);
    kselect<<<2, 256, 0, stream>>>(divavg, imp, keep);
    kgather<<<2016, 256, 0, stream>>>(past_k, past_v, Kpart, Vnew, keep, Kg, VTg);
    attn<<<2048, 128, 0, stream>>>(Qbf, Kg, VTg, Opart, Lpart);
    kmerge<<<2048, 256, 0, stream>>>(Opart, Lpart, attnbf);
    gemm_proj64<<<512, 256, 0, stream>>>(attnbf, wproj, proj_b, out);
}